// Round 1
// baseline (585.697 us; speedup 1.0000x reference)
//
#include <hip/hip_runtime.h>
#include <hip/hip_bf16.h>
#include <stdint.h>

// ---- constants for this problem ----
// B=4, S=4096, D=1024, M=4096. DECAY=0.9
#define BSZ 4
#define SEQ 4096
#define DIM 1024
#define MDIM 4096
#define DECAYF 0.9f
#define OMD 0.1f
#define CHUNK 128
#define NCHUNK 32           // SEQ / CHUNK
#define DECAY_CHUNK 1.3901844577868923e-06f  // 0.9^128

typedef __bf16 bf16_t;
typedef __bf16 bf16x8 __attribute__((ext_vector_type(8)));
typedef __bf16 bf16x4 __attribute__((ext_vector_type(4)));
typedef float floatx4 __attribute__((ext_vector_type(4)));

// ---- async global->LDS, 16B per lane. lds ptr must be wave-uniform base;
//      HW writes lane i at base + i*16 (m97 pattern). ----
__device__ __forceinline__ void load16_lds(const void* g, void* l) {
  __builtin_amdgcn_global_load_lds(
      (__attribute__((address_space(1))) void*)g,
      (__attribute__((address_space(3))) void*)l,
      16, 0, 0);
}

// ---------------- scan kernels ----------------
// thread t over [0, B*NCHUNK*DIM): d = t&1023, c = (t>>10)&31, b = t>>15
__global__ void scan_chunk_kernel(const float* __restrict__ x,
                                  float* __restrict__ chunk_end) {
  int t = blockIdx.x * 256 + threadIdx.x;
  int d = t & (DIM - 1);
  int c = (t >> 10) & (NCHUNK - 1);
  int b = t >> 15;
  const float* xp = x + ((size_t)(b * SEQ + c * CHUNK)) * DIM + d;
  float p = 0.f;
#pragma unroll 8
  for (int s = 0; s < CHUNK; ++s) p = DECAYF * p + OMD * xp[(size_t)s * DIM];
  chunk_end[t] = p;
}

// thread t over [0, B*DIM): b = t>>10, d = t&1023
__global__ void scan_carry_kernel(const float* __restrict__ chunk_end,
                                  float* __restrict__ carry_in,
                                  float* __restrict__ final_state) {
  int t = blockIdx.x * 256 + threadIdx.x;
  int d = t & (DIM - 1);
  int b = t >> 10;
  float carry = 0.f;
#pragma unroll
  for (int c = 0; c < NCHUNK; ++c) {
    int idx = (b * NCHUNK + c) * DIM + d;
    carry_in[idx] = carry;
    carry = carry * DECAY_CHUNK + chunk_end[idx];
  }
  final_state[t] = carry;  // == current_states[b, S-1, d]
}

__global__ void scan_emit_kernel(const float* __restrict__ x,
                                 const float* __restrict__ carry_in,
                                 bf16_t* __restrict__ prev) {
  int t = blockIdx.x * 256 + threadIdx.x;
  int d = t & (DIM - 1);
  int c = (t >> 10) & (NCHUNK - 1);
  int b = t >> 15;
  size_t base = ((size_t)(b * SEQ + c * CHUNK)) * DIM + d;
  const float* xp = x + base;
  bf16_t* pp = prev + base;
  float cs = carry_in[t];  // == current_states[b, c*CHUNK - 1, d]
#pragma unroll 4
  for (int s = 0; s < CHUNK; ++s) {
    pp[(size_t)s * DIM] = (bf16_t)cs;   // prev[t] = cs[t-1]
    cs = DECAYF * cs + OMD * xp[(size_t)s * DIM];
  }
}

// ---------------- fp32 -> bf16 convert (4 elems / thread) ----------------
__global__ void cvt_bf16_kernel(const float* __restrict__ w, bf16_t* __restrict__ o) {
  int t = blockIdx.x * 256 + threadIdx.x;
  float4 v = ((const float4*)w)[t];
  bf16x4 r = { (bf16_t)v.x, (bf16_t)v.y, (bf16_t)v.z, (bf16_t)v.w };
  ((bf16x4*)o)[t] = r;
}

// ---------------- GEMM: C[M][N] = A[M][K] * B[N][K]^T  (both K-contiguous bf16)
// 128x128 tile, BK=64, 256 threads (4 waves, each 64x64), 16x16x32 bf16 MFMA.
// EPI==0: silu -> bf16 store.  EPI==1: fp32 store + fused MSE partial vs X.
template <int N, int K, int EPI>
__global__ __launch_bounds__(256) void gemm_bt_kernel(
    const bf16_t* __restrict__ A, const bf16_t* __restrict__ B,
    void* __restrict__ Cout, const float* __restrict__ X,
    float* __restrict__ loss_acc) {
  __shared__ __attribute__((aligned(16))) bf16_t sA[128 * 64];
  __shared__ __attribute__((aligned(16))) bf16_t sB[128 * 64];

  const int tid = threadIdx.x;
  const int wave = tid >> 6;
  const int lane = tid & 63;
  const int tm = blockIdx.y * 128;
  const int tn = blockIdx.x * 128;
  const int lrow = lane >> 3;        // row within 8-row staging group
  const int lcol = (lane & 7) * 8;   // element col within BK
  const int wm = (wave & 1) * 64;    // wave sub-tile origin
  const int wn = (wave >> 1) * 64;

  floatx4 acc[4][4];
#pragma unroll
  for (int i = 0; i < 4; ++i)
#pragma unroll
    for (int j = 0; j < 4; ++j) acc[i][j] = (floatx4){0.f, 0.f, 0.f, 0.f};

#pragma unroll 1
  for (int kt = 0; kt < K; kt += 64) {
    __syncthreads();  // previous iteration's LDS reads done before overwrite
#pragma unroll
    for (int j = 0; j < 4; ++j) {
      const int g = j * 4 + wave;  // 16 groups of 8 rows
      const bf16_t* ga = A + (size_t)(tm + g * 8 + lrow) * K + kt + lcol;
      load16_lds(ga, (char*)sA + g * 1024);
      const bf16_t* gb = B + (size_t)(tn + g * 8 + lrow) * K + kt + lcol;
      load16_lds(gb, (char*)sB + g * 1024);
    }
    __syncthreads();  // drains vmcnt(0): staged data visible
#pragma unroll
    for (int ks = 0; ks < 2; ++ks) {
      const int kk = ks * 32 + (lane >> 4) * 8;
      bf16x8 af[4], bfr[4];
#pragma unroll
      for (int i = 0; i < 4; ++i)
        af[i] = *(const bf16x8*)&sA[(size_t)(wm + i * 16 + (lane & 15)) * 64 + kk];
#pragma unroll
      for (int j = 0; j < 4; ++j)
        bfr[j] = *(const bf16x8*)&sB[(size_t)(wn + j * 16 + (lane & 15)) * 64 + kk];
#pragma unroll
      for (int i = 0; i < 4; ++i)
#pragma unroll
        for (int j = 0; j < 4; ++j)
          acc[i][j] = __builtin_amdgcn_mfma_f32_16x16x32_bf16(af[i], bfr[j],
                                                              acc[i][j], 0, 0, 0);
    }
  }

  // epilogue. C/D frag: col = lane&15, row = (lane>>4)*4 + reg
  const int r0 = (lane >> 4) * 4;
  const int cn = lane & 15;
  if constexpr (EPI == 0) {
    bf16_t* H = (bf16_t*)Cout;
#pragma unroll
    for (int i = 0; i < 4; ++i)
#pragma unroll
      for (int j = 0; j < 4; ++j)
#pragma unroll
        for (int r = 0; r < 4; ++r) {
          int m = tm + wm + i * 16 + r0 + r;
          int n = tn + wn + j * 16 + cn;
          float v = acc[i][j][r];
          v = v / (1.f + __expf(-v));  // silu
          H[(size_t)m * N + n] = (bf16_t)v;
        }
  } else {
    float* O = (float*)Cout;
    float ls = 0.f;
#pragma unroll
    for (int i = 0; i < 4; ++i)
#pragma unroll
      for (int j = 0; j < 4; ++j)
#pragma unroll
        for (int r = 0; r < 4; ++r) {
          int m = tm + wm + i * 16 + r0 + r;
          int n = tn + wn + j * 16 + cn;
          size_t off = (size_t)m * N + n;
          float v = acc[i][j][r];
          O[off] = v;
          float dd = v - X[off];
          ls += dd * dd;
        }
    // wave reduction then one atomic per wave
#pragma unroll
    for (int s = 32; s > 0; s >>= 1) ls += __shfl_down(ls, s, 64);
    if (lane == 0) atomicAdd(loss_acc, ls);
  }
}

__global__ void finalize_loss_kernel(const float* __restrict__ loss_acc,
                                     float* __restrict__ out) {
  if (threadIdx.x == 0)
    out[0] = loss_acc[0] * (1.0f / (float)(BSZ * SEQ * DIM));
}

// ---------------- launch ----------------
extern "C" void kernel_launch(void* const* d_in, const int* in_sizes, int n_in,
                              void* d_out, int out_size, void* d_ws, size_t ws_size,
                              hipStream_t stream) {
  const float* x  = (const float*)d_in[0];   // [4][4096][1024]
  const float* w1 = (const float*)d_in[1];   // [4096][1024]
  const float* w2 = (const float*)d_in[2];   // [1024][4096]
  float* out = (float*)d_out;                // mem_out | loss | final_state

  const int BT = BSZ * SEQ;                  // 16384 rows
  char* ws = (char*)d_ws;
  // workspace layout (bytes)
  bf16_t* prev      = (bf16_t*)(ws);                      // 16M bf16  = 33,554,432 B
  bf16_t* h         = (bf16_t*)(ws + 33554432ull);        // 64M bf16  = 134,217,728 B
  bf16_t* w1b       = (bf16_t*)(ws + 167772160ull);       // 4M bf16   = 8,388,608 B
  bf16_t* w2b       = (bf16_t*)(ws + 176160768ull);       // 4M bf16   = 8,388,608 B
  float*  chunk_end = (float*)(ws + 184549376ull);        // 128K f32  = 524,288 B
  float*  carry_in  = (float*)(ws + 185073664ull);        // 128K f32  = 524,288 B
  float*  loss_acc  = (float*)(ws + 185597952ull);        // 4 B

  hipMemsetAsync(loss_acc, 0, sizeof(float), stream);

  // weights -> bf16 (4,194,304 elems each; 4/thread)
  cvt_bf16_kernel<<<4096, 256, 0, stream>>>(w1, w1b);
  cvt_bf16_kernel<<<4096, 256, 0, stream>>>(w2, w2b);

  // chunked EMA scan -> prev states (bf16) + final_state (fp32, d_out tail)
  scan_chunk_kernel<<<(BSZ * NCHUNK * DIM) / 256, 256, 0, stream>>>(x, chunk_end);
  scan_carry_kernel<<<(BSZ * DIM) / 256, 256, 0, stream>>>(chunk_end, carry_in,
                                                           out + 16777217);
  scan_emit_kernel<<<(BSZ * NCHUNK * DIM) / 256, 256, 0, stream>>>(x, carry_in, prev);

  // h = silu(prev @ w1^T)  : [16384 x 1024] x [4096 x 1024]^T -> bf16 [16384 x 4096]
  gemm_bt_kernel<MDIM, DIM, 0>
      <<<dim3(MDIM / 128, BT / 128), 256, 0, stream>>>(prev, w1b, h, nullptr, nullptr);

  // mem_out = h @ w2^T : [16384 x 4096] x [1024 x 4096]^T -> fp32 [16384 x 1024]
  // fused: loss partial sums vs x
  gemm_bt_kernel<DIM, MDIM, 1>
      <<<dim3(DIM / 128, BT / 128), 256, 0, stream>>>(h, w2b, out, x, loss_acc);

  finalize_loss_kernel<<<1, 64, 0, stream>>>(loss_acc, out + 16777216);
}

// Round 2
// 546.803 us; speedup vs baseline: 1.0711x; 1.0711x over previous
//
#include <hip/hip_runtime.h>
#include <hip/hip_bf16.h>
#include <stdint.h>

// ---- constants for this problem ----
// B=4, S=4096, D=1024, M=4096. DECAY=0.9
#define BSZ 4
#define SEQ 4096
#define DIM 1024
#define MDIM 4096
#define DECAYF 0.9f
#define OMD 0.1f
#define CHUNK 128
#define NCHUNK 32           // SEQ / CHUNK
#define DECAY_CHUNK 1.3901844577868923e-06f  // 0.9^128

typedef __bf16 bf16_t;
typedef __bf16 bf16x8 __attribute__((ext_vector_type(8)));
typedef __bf16 bf16x4 __attribute__((ext_vector_type(4)));
typedef float floatx4 __attribute__((ext_vector_type(4)));

// ---- async global->LDS, 16B per lane. lds ptr must be wave-uniform base;
//      HW writes lane i at base + i*16 (m97 pattern). ----
__device__ __forceinline__ void load16_lds(const void* g, void* l) {
  __builtin_amdgcn_global_load_lds(
      (__attribute__((address_space(1))) void*)g,
      (__attribute__((address_space(3))) void*)l,
      16, 0, 0);
}

// ---------------- scan kernels ----------------
// thread t over [0, B*NCHUNK*DIM): d = t&1023, c = (t>>10)&31, b = t>>15
__global__ void scan_chunk_kernel(const float* __restrict__ x,
                                  float* __restrict__ chunk_end) {
  int t = blockIdx.x * 256 + threadIdx.x;
  int d = t & (DIM - 1);
  int c = (t >> 10) & (NCHUNK - 1);
  int b = t >> 15;
  const float* xp = x + ((size_t)(b * SEQ + c * CHUNK)) * DIM + d;
  float p = 0.f;
#pragma unroll 8
  for (int s = 0; s < CHUNK; ++s) p = DECAYF * p + OMD * xp[(size_t)s * DIM];
  chunk_end[t] = p;
}

// thread t over [0, B*DIM): b = t>>10, d = t&1023
__global__ void scan_carry_kernel(const float* __restrict__ chunk_end,
                                  float* __restrict__ carry_in,
                                  float* __restrict__ final_state) {
  int t = blockIdx.x * 256 + threadIdx.x;
  int d = t & (DIM - 1);
  int b = t >> 10;
  float carry = 0.f;
#pragma unroll
  for (int c = 0; c < NCHUNK; ++c) {
    int idx = (b * NCHUNK + c) * DIM + d;
    carry_in[idx] = carry;
    carry = carry * DECAY_CHUNK + chunk_end[idx];
  }
  final_state[t] = carry;  // == current_states[b, S-1, d]
}

__global__ void scan_emit_kernel(const float* __restrict__ x,
                                 const float* __restrict__ carry_in,
                                 bf16_t* __restrict__ prev) {
  int t = blockIdx.x * 256 + threadIdx.x;
  int d = t & (DIM - 1);
  int c = (t >> 10) & (NCHUNK - 1);
  int b = t >> 15;
  size_t base = ((size_t)(b * SEQ + c * CHUNK)) * DIM + d;
  const float* xp = x + base;
  bf16_t* pp = prev + base;
  float cs = carry_in[t];  // == current_states[b, c*CHUNK - 1, d]
#pragma unroll 4
  for (int s = 0; s < CHUNK; ++s) {
    pp[(size_t)s * DIM] = (bf16_t)cs;   // prev[t] = cs[t-1]
    cs = DECAYF * cs + OMD * xp[(size_t)s * DIM];
  }
}

// ---------------- fp32 -> bf16 convert (4 elems / thread) ----------------
__global__ void cvt_bf16_kernel(const float* __restrict__ w, bf16_t* __restrict__ o) {
  int t = blockIdx.x * 256 + threadIdx.x;
  float4 v = ((const float4*)w)[t];
  bf16x4 r = { (bf16_t)v.x, (bf16_t)v.y, (bf16_t)v.z, (bf16_t)v.w };
  ((bf16x4*)o)[t] = r;
}

// ---------------- GEMM: C[M][N] = A[M][K] * B[N][K]^T  (both K-contiguous bf16)
// 128x128 tile, BK=64, 256 threads (4 waves, each 64x64), 16x16x32 bf16 MFMA.
// LDS layout XOR-swizzled: physical 16B-chunk p of row r holds logical chunk
// p ^ (r&7). Staging achieves this by permuting the per-lane GLOBAL source
// (write side is fixed at base+lane*16); reads apply the same involution.
// This removes the 128B-row-stride bank-group pileup (R1: 5e7 conflict cyc).
// EPI==0: silu -> bf16 store.  EPI==1: fp32 store + fused MSE partial vs X.
template <int N, int K, int EPI>
__global__ __launch_bounds__(256) void gemm_bt_kernel(
    const bf16_t* __restrict__ A, const bf16_t* __restrict__ B,
    void* __restrict__ Cout, const float* __restrict__ X,
    float* __restrict__ loss_acc) {
  __shared__ __attribute__((aligned(16))) bf16_t sA[128 * 64];
  __shared__ __attribute__((aligned(16))) bf16_t sB[128 * 64];

  const int tid = threadIdx.x;
  const int wave = tid >> 6;
  const int lane = tid & 63;
  const int tm = blockIdx.y * 128;
  const int tn = blockIdx.x * 128;
  const int lrow = lane >> 3;                    // row within 8-row staging group
  const int lcol = ((lane & 7) ^ lrow) * 8;      // swizzled source chunk
  const int wm = (wave & 1) * 64;    // wave sub-tile origin
  const int wn = (wave >> 1) * 64;

  floatx4 acc[4][4];
#pragma unroll
  for (int i = 0; i < 4; ++i)
#pragma unroll
    for (int j = 0; j < 4; ++j) acc[i][j] = (floatx4){0.f, 0.f, 0.f, 0.f};

#pragma unroll 1
  for (int kt = 0; kt < K; kt += 64) {
    __syncthreads();  // previous iteration's LDS reads done before overwrite
#pragma unroll
    for (int j = 0; j < 4; ++j) {
      const int g = j * 4 + wave;  // 16 groups of 8 rows
      const bf16_t* ga = A + (size_t)(tm + g * 8 + lrow) * K + kt + lcol;
      load16_lds(ga, (char*)sA + g * 1024);
      const bf16_t* gb = B + (size_t)(tn + g * 8 + lrow) * K + kt + lcol;
      load16_lds(gb, (char*)sB + g * 1024);
    }
    __syncthreads();  // drains vmcnt(0): staged data visible
#pragma unroll
    for (int ks = 0; ks < 2; ++ks) {
      // logical chunk = ks*4 + (lane>>4); row&7 == lane&7 for every fragment
      // (tile origins are multiples of 8), so one swizzled offset serves all.
      const int pchunk = (((ks * 4) + (lane >> 4)) ^ (lane & 7)) * 8;
      bf16x8 af[4], bfr[4];
#pragma unroll
      for (int i = 0; i < 4; ++i)
        af[i] = *(const bf16x8*)&sA[(size_t)(wm + i * 16 + (lane & 15)) * 64 + pchunk];
#pragma unroll
      for (int j = 0; j < 4; ++j)
        bfr[j] = *(const bf16x8*)&sB[(size_t)(wn + j * 16 + (lane & 15)) * 64 + pchunk];
#pragma unroll
      for (int i = 0; i < 4; ++i)
#pragma unroll
        for (int j = 0; j < 4; ++j)
          acc[i][j] = __builtin_amdgcn_mfma_f32_16x16x32_bf16(af[i], bfr[j],
                                                              acc[i][j], 0, 0, 0);
    }
  }

  // epilogue. C/D frag: col = lane&15, row = (lane>>4)*4 + reg
  const int r0 = (lane >> 4) * 4;
  const int cn = lane & 15;
  if constexpr (EPI == 0) {
    bf16_t* H = (bf16_t*)Cout;
#pragma unroll
    for (int i = 0; i < 4; ++i)
#pragma unroll
      for (int j = 0; j < 4; ++j)
#pragma unroll
        for (int r = 0; r < 4; ++r) {
          int m = tm + wm + i * 16 + r0 + r;
          int n = tn + wn + j * 16 + cn;
          float v = acc[i][j][r];
          v = v / (1.f + __expf(-v));  // silu
          H[(size_t)m * N + n] = (bf16_t)v;
        }
  } else {
    float* O = (float*)Cout;
    float ls = 0.f;
#pragma unroll
    for (int i = 0; i < 4; ++i)
#pragma unroll
      for (int j = 0; j < 4; ++j)
#pragma unroll
        for (int r = 0; r < 4; ++r) {
          int m = tm + wm + i * 16 + r0 + r;
          int n = tn + wn + j * 16 + cn;
          size_t off = (size_t)m * N + n;
          float v = acc[i][j][r];
          O[off] = v;
          float dd = v - X[off];
          ls += dd * dd;
        }
    // wave reduction then one atomic per wave
#pragma unroll
    for (int s = 32; s > 0; s >>= 1) ls += __shfl_down(ls, s, 64);
    if (lane == 0) atomicAdd(loss_acc, ls);
  }
}

__global__ void finalize_loss_kernel(const float* __restrict__ loss_acc,
                                     float* __restrict__ out) {
  if (threadIdx.x == 0)
    out[0] = loss_acc[0] * (1.0f / (float)(BSZ * SEQ * DIM));
}

// ---------------- launch ----------------
extern "C" void kernel_launch(void* const* d_in, const int* in_sizes, int n_in,
                              void* d_out, int out_size, void* d_ws, size_t ws_size,
                              hipStream_t stream) {
  const float* x  = (const float*)d_in[0];   // [4][4096][1024]
  const float* w1 = (const float*)d_in[1];   // [4096][1024]
  const float* w2 = (const float*)d_in[2];   // [1024][4096]
  float* out = (float*)d_out;                // mem_out | loss | final_state

  const int BT = BSZ * SEQ;                  // 16384 rows
  char* ws = (char*)d_ws;
  // workspace layout (bytes)
  bf16_t* prev      = (bf16_t*)(ws);                      // 16M bf16  = 33,554,432 B
  bf16_t* h         = (bf16_t*)(ws + 33554432ull);        // 64M bf16  = 134,217,728 B
  bf16_t* w1b       = (bf16_t*)(ws + 167772160ull);       // 4M bf16   = 8,388,608 B
  bf16_t* w2b       = (bf16_t*)(ws + 176160768ull);       // 4M bf16   = 8,388,608 B
  float*  chunk_end = (float*)(ws + 184549376ull);        // 128K f32  = 524,288 B
  float*  carry_in  = (float*)(ws + 185073664ull);        // 128K f32  = 524,288 B
  float*  loss_acc  = (float*)(ws + 185597952ull);        // 4 B

  hipMemsetAsync(loss_acc, 0, sizeof(float), stream);

  // weights -> bf16 (4,194,304 elems each; 4/thread)
  cvt_bf16_kernel<<<4096, 256, 0, stream>>>(w1, w1b);
  cvt_bf16_kernel<<<4096, 256, 0, stream>>>(w2, w2b);

  // chunked EMA scan -> prev states (bf16) + final_state (fp32, d_out tail)
  scan_chunk_kernel<<<(BSZ * NCHUNK * DIM) / 256, 256, 0, stream>>>(x, chunk_end);
  scan_carry_kernel<<<(BSZ * DIM) / 256, 256, 0, stream>>>(chunk_end, carry_in,
                                                           out + 16777217);
  scan_emit_kernel<<<(BSZ * NCHUNK * DIM) / 256, 256, 0, stream>>>(x, carry_in, prev);

  // h = silu(prev @ w1^T)  : [16384 x 1024] x [4096 x 1024]^T -> bf16 [16384 x 4096]
  gemm_bt_kernel<MDIM, DIM, 0>
      <<<dim3(MDIM / 128, BT / 128), 256, 0, stream>>>(prev, w1b, h, nullptr, nullptr);

  // mem_out = h @ w2^T : [16384 x 4096] x [1024 x 4096]^T -> fp32 [16384 x 1024]
  // fused: loss partial sums vs x
  gemm_bt_kernel<DIM, MDIM, 1>
      <<<dim3(DIM / 128, BT / 128), 256, 0, stream>>>(h, w2b, out, x, loss_acc);

  finalize_loss_kernel<<<1, 64, 0, stream>>>(loss_acc, out + 16777216);
}

// Round 3
// 534.158 us; speedup vs baseline: 1.0965x; 1.0237x over previous
//
#include <hip/hip_runtime.h>
#include <hip/hip_bf16.h>
#include <stdint.h>

// ---- constants for this problem ----
// B=4, S=4096, D=1024, M=4096. DECAY=0.9
#define BSZ 4
#define SEQ 4096
#define DIM 1024
#define MDIM 4096
#define DECAYF 0.9f
#define OMD 0.1f
#define CHUNK 128
#define NCHUNK 32           // SEQ / CHUNK
#define DECAY_CHUNK 1.3901844577868923e-06f  // 0.9^128

typedef __bf16 bf16_t;
typedef __bf16 bf16x8 __attribute__((ext_vector_type(8)));
typedef __bf16 bf16x4 __attribute__((ext_vector_type(4)));
typedef float floatx4 __attribute__((ext_vector_type(4)));

// ---- async global->LDS, 16B per lane. lds ptr must be wave-uniform base;
//      HW writes lane i at base + i*16 (m97 pattern). ----
__device__ __forceinline__ void load16_lds(const void* g, void* l) {
  __builtin_amdgcn_global_load_lds(
      (__attribute__((address_space(1))) void*)g,
      (__attribute__((address_space(3))) void*)l,
      16, 0, 0);
}

// ---------------- scan kernels ----------------
__global__ void scan_chunk_kernel(const float* __restrict__ x,
                                  float* __restrict__ chunk_end) {
  int t = blockIdx.x * 256 + threadIdx.x;
  int d = t & (DIM - 1);
  int c = (t >> 10) & (NCHUNK - 1);
  int b = t >> 15;
  const float* xp = x + ((size_t)(b * SEQ + c * CHUNK)) * DIM + d;
  float p = 0.f;
#pragma unroll 8
  for (int s = 0; s < CHUNK; ++s) p = DECAYF * p + OMD * xp[(size_t)s * DIM];
  chunk_end[t] = p;
}

__global__ void scan_carry_kernel(const float* __restrict__ chunk_end,
                                  float* __restrict__ carry_in,
                                  float* __restrict__ final_state) {
  int t = blockIdx.x * 256 + threadIdx.x;
  int d = t & (DIM - 1);
  int b = t >> 10;
  float carry = 0.f;
#pragma unroll
  for (int c = 0; c < NCHUNK; ++c) {
    int idx = (b * NCHUNK + c) * DIM + d;
    carry_in[idx] = carry;
    carry = carry * DECAY_CHUNK + chunk_end[idx];
  }
  final_state[t] = carry;  // == current_states[b, S-1, d]
}

__global__ void scan_emit_kernel(const float* __restrict__ x,
                                 const float* __restrict__ carry_in,
                                 bf16_t* __restrict__ prev) {
  int t = blockIdx.x * 256 + threadIdx.x;
  int d = t & (DIM - 1);
  int c = (t >> 10) & (NCHUNK - 1);
  int b = t >> 15;
  size_t base = ((size_t)(b * SEQ + c * CHUNK)) * DIM + d;
  const float* xp = x + base;
  bf16_t* pp = prev + base;
  float cs = carry_in[t];  // == current_states[b, c*CHUNK - 1, d]
#pragma unroll 4
  for (int s = 0; s < CHUNK; ++s) {
    pp[(size_t)s * DIM] = (bf16_t)cs;   // prev[t] = cs[t-1]
    cs = DECAYF * cs + OMD * xp[(size_t)s * DIM];
  }
}

// ---------------- fp32 -> bf16 convert (4 elems / thread) ----------------
__global__ void cvt_bf16_kernel(const float* __restrict__ w, bf16_t* __restrict__ o) {
  int t = blockIdx.x * 256 + threadIdx.x;
  float4 v = ((const float4*)w)[t];
  bf16x4 r = { (bf16_t)v.x, (bf16_t)v.y, (bf16_t)v.z, (bf16_t)v.w };
  ((bf16x4*)o)[t] = r;
}

// ---------------- GEMM: C[M][N] = A[M][K] * B[N][K]^T  (both K-contiguous bf16)
// 128x128 tile, BK=64, 256 threads (4 waves, each 64x64), 16x16x32 bf16 MFMA.
// LDS XOR-swizzled (R2: conflicts 5e7 -> 0).
// XCD-aware 1D grid remap (R3): bid%8 selects XCD [heuristic, speed-only];
// blocks sharing one A-tile (same m, all n) are consecutive slots on the SAME
// XCD, so A-tile reuse hits the local 4MiB L2 instead of refetching HBM
// (R2 evidence: GEMM2 FETCH 565MB vs ~210MB ideal — h refetched ~4x via
// thrashed LLC because bid%8 == n spread A-sharers across all 8 XCDs).
// MT = M/128 m-tiles (must be %8==0), NT = N/128 n-tiles.
// EPI==0: silu -> bf16 store.  EPI==1: fp32 store + fused MSE partial vs X.
template <int N, int K, int MT, int EPI>
__global__ __launch_bounds__(256) void gemm_bt_kernel(
    const bf16_t* __restrict__ A, const bf16_t* __restrict__ B,
    void* __restrict__ Cout, const float* __restrict__ X,
    float* __restrict__ loss_acc) {
  constexpr int NT = N / 128;
  __shared__ __attribute__((aligned(16))) bf16_t sA[128 * 64];
  __shared__ __attribute__((aligned(16))) bf16_t sB[128 * 64];

  const int tid = threadIdx.x;
  const int wave = tid >> 6;
  const int lane = tid & 63;
  // XCD-aware remap: all NT n-tiles of one m-tile are adjacent slots on one XCD.
  const int bid = blockIdx.x;
  const int xcd = bid & 7;
  const int slot = bid >> 3;
  const int tm = (xcd * (MT / 8) + slot / NT) * 128;
  const int tn = (slot % NT) * 128;
  const int lrow = lane >> 3;                    // row within 8-row staging group
  const int lcol = ((lane & 7) ^ lrow) * 8;      // swizzled source chunk
  const int wm = (wave & 1) * 64;    // wave sub-tile origin
  const int wn = (wave >> 1) * 64;

  floatx4 acc[4][4];
#pragma unroll
  for (int i = 0; i < 4; ++i)
#pragma unroll
    for (int j = 0; j < 4; ++j) acc[i][j] = (floatx4){0.f, 0.f, 0.f, 0.f};

#pragma unroll 1
  for (int kt = 0; kt < K; kt += 64) {
    __syncthreads();  // previous iteration's LDS reads done before overwrite
#pragma unroll
    for (int j = 0; j < 4; ++j) {
      const int g = j * 4 + wave;  // 16 groups of 8 rows
      const bf16_t* ga = A + (size_t)(tm + g * 8 + lrow) * K + kt + lcol;
      load16_lds(ga, (char*)sA + g * 1024);
      const bf16_t* gb = B + (size_t)(tn + g * 8 + lrow) * K + kt + lcol;
      load16_lds(gb, (char*)sB + g * 1024);
    }
    __syncthreads();  // drains vmcnt(0): staged data visible
#pragma unroll
    for (int ks = 0; ks < 2; ++ks) {
      // logical chunk = ks*4 + (lane>>4); row&7 == lane&7 for every fragment
      // (tile origins are multiples of 8), so one swizzled offset serves all.
      const int pchunk = (((ks * 4) + (lane >> 4)) ^ (lane & 7)) * 8;
      bf16x8 af[4], bfr[4];
#pragma unroll
      for (int i = 0; i < 4; ++i)
        af[i] = *(const bf16x8*)&sA[(size_t)(wm + i * 16 + (lane & 15)) * 64 + pchunk];
#pragma unroll
      for (int j = 0; j < 4; ++j)
        bfr[j] = *(const bf16x8*)&sB[(size_t)(wn + j * 16 + (lane & 15)) * 64 + pchunk];
#pragma unroll
      for (int i = 0; i < 4; ++i)
#pragma unroll
        for (int j = 0; j < 4; ++j)
          acc[i][j] = __builtin_amdgcn_mfma_f32_16x16x32_bf16(af[i], bfr[j],
                                                              acc[i][j], 0, 0, 0);
    }
  }

  // epilogue. C/D frag: col = lane&15, row = (lane>>4)*4 + reg
  const int r0 = (lane >> 4) * 4;
  const int cn = lane & 15;
  if constexpr (EPI == 0) {
    bf16_t* H = (bf16_t*)Cout;
#pragma unroll
    for (int i = 0; i < 4; ++i)
#pragma unroll
      for (int j = 0; j < 4; ++j)
#pragma unroll
        for (int r = 0; r < 4; ++r) {
          int m = tm + wm + i * 16 + r0 + r;
          int n = tn + wn + j * 16 + cn;
          float v = acc[i][j][r];
          v = v / (1.f + __expf(-v));  // silu
          H[(size_t)m * N + n] = (bf16_t)v;
        }
  } else {
    float* O = (float*)Cout;
    float ls = 0.f;
#pragma unroll
    for (int i = 0; i < 4; ++i)
#pragma unroll
      for (int j = 0; j < 4; ++j)
#pragma unroll
        for (int r = 0; r < 4; ++r) {
          int m = tm + wm + i * 16 + r0 + r;
          int n = tn + wn + j * 16 + cn;
          size_t off = (size_t)m * N + n;
          float v = acc[i][j][r];
          O[off] = v;
          float dd = v - X[off];
          ls += dd * dd;
        }
    // wave reduction then one atomic per wave
#pragma unroll
    for (int s = 32; s > 0; s >>= 1) ls += __shfl_down(ls, s, 64);
    if (lane == 0) atomicAdd(loss_acc, ls);
  }
}

__global__ void finalize_loss_kernel(const float* __restrict__ loss_acc,
                                     float* __restrict__ out) {
  if (threadIdx.x == 0)
    out[0] = loss_acc[0] * (1.0f / (float)(BSZ * SEQ * DIM));
}

// ---------------- launch ----------------
extern "C" void kernel_launch(void* const* d_in, const int* in_sizes, int n_in,
                              void* d_out, int out_size, void* d_ws, size_t ws_size,
                              hipStream_t stream) {
  const float* x  = (const float*)d_in[0];   // [4][4096][1024]
  const float* w1 = (const float*)d_in[1];   // [4096][1024]
  const float* w2 = (const float*)d_in[2];   // [1024][4096]
  float* out = (float*)d_out;                // mem_out | loss | final_state

  const int BT = BSZ * SEQ;                  // 16384 rows, 128 m-tiles
  char* ws = (char*)d_ws;
  // workspace layout (bytes)
  bf16_t* prev      = (bf16_t*)(ws);                      // 16M bf16  = 33,554,432 B
  bf16_t* h         = (bf16_t*)(ws + 33554432ull);        // 64M bf16  = 134,217,728 B
  bf16_t* w1b       = (bf16_t*)(ws + 167772160ull);       // 4M bf16   = 8,388,608 B
  bf16_t* w2b       = (bf16_t*)(ws + 176160768ull);       // 4M bf16   = 8,388,608 B
  float*  chunk_end = (float*)(ws + 184549376ull);        // 128K f32  = 524,288 B
  float*  carry_in  = (float*)(ws + 185073664ull);        // 128K f32  = 524,288 B
  float*  loss_acc  = (float*)(ws + 185597952ull);        // 4 B

  hipMemsetAsync(loss_acc, 0, sizeof(float), stream);

  // weights -> bf16 (4,194,304 elems each; 4/thread)
  cvt_bf16_kernel<<<4096, 256, 0, stream>>>(w1, w1b);
  cvt_bf16_kernel<<<4096, 256, 0, stream>>>(w2, w2b);

  // chunked EMA scan -> prev states (bf16) + final_state (fp32, d_out tail)
  scan_chunk_kernel<<<(BSZ * NCHUNK * DIM) / 256, 256, 0, stream>>>(x, chunk_end);
  scan_carry_kernel<<<(BSZ * DIM) / 256, 256, 0, stream>>>(chunk_end, carry_in,
                                                           out + 16777217);
  scan_emit_kernel<<<(BSZ * NCHUNK * DIM) / 256, 256, 0, stream>>>(x, carry_in, prev);

  // h = silu(prev @ w1^T)  : [16384 x 1024] x [4096 x 1024]^T -> bf16 [16384 x 4096]
  gemm_bt_kernel<MDIM, DIM, BT / 128, 0>
      <<<(BT / 128) * (MDIM / 128), 256, 0, stream>>>(prev, w1b, h, nullptr, nullptr);

  // mem_out = h @ w2^T : [16384 x 4096] x [1024 x 4096]^T -> fp32 [16384 x 1024]
  // fused: loss partial sums vs x
  gemm_bt_kernel<DIM, MDIM, BT / 128, 1>
      <<<(BT / 128) * (DIM / 128), 256, 0, stream>>>(h, w2b, out, x, loss_acc);

  finalize_loss_kernel<<<1, 64, 0, stream>>>(loss_acc, out + 16777216);
}